// Round 9
// baseline (160.564 us; speedup 1.0000x reference)
//
#include <hip/hip_runtime.h>
#include <math.h>

#define CC 1024
#define SS 16
#define DD 512
#define RR (CC*SS)
#define EPSV 1e-8f
#define LDX 516    // k_pre LDS row stride (floats)

typedef __attribute__((ext_vector_type(8))) short short8;
typedef __attribute__((ext_vector_type(4))) float f32x4;
typedef unsigned short ushort_t;

__device__ __forceinline__ unsigned short f2bf(float f) {
  unsigned u = __float_as_uint(f);
  u += 0x7fffu + ((u >> 16) & 1u);  // RNE
  return (unsigned short)(u >> 16);
}

__device__ __forceinline__ float softplusf(float v) {
  return (v > 20.f) ? v : log1pf(expf(v));
}

// ---------------- Kernel 1: per-class precompute ----------------
// xn written in MFMA A-fragment order (16B units [class][kc][quad][cL]).
// mn is now ALSO written in B-fragment order:
//   mnf unit idx = (ftile*16 + kc)*64 + quad*16 + cL   (ftile = class>>4)
// so k_gemm reads each B-fragment as ONE coalesced 1KB wave load from
// global (L2-resident; 1MB total) -- no LDS staging, no barriers.
__global__ __launch_bounds__(256) void k_pre(
    const float* __restrict__ x, ushort_t* __restrict__ mnf,
    float* __restrict__ nx, float* __restrict__ simpos,
    ushort_t* __restrict__ xn) {
  __shared__ float xs[SS * LDX];
  __shared__ float sums[DD];
  __shared__ float red[4];
  __shared__ float snm;
  __shared__ float rinv[SS];
  __shared__ ushort_t mrow[DD];
  const int j = blockIdx.x, tid = threadIdx.x;
  const int wid = tid >> 6, lane = tid & 63;
  const float4* xj = (const float4*)(x + (size_t)j * SS * DD);
#pragma unroll
  for (int t = 0; t < 8; ++t) {
    const int idx = tid + t * 256;          // 2048 float4 units
    const int row = idx >> 7, d4 = idx & 127;
    *(float4*)(xs + row * LDX + d4 * 4) = xj[idx];
  }
  __syncthreads();

  // column sums (each thread owns a float2 column pair, kept in regs)
  float sx = 0.f, sy = 0.f;
#pragma unroll
  for (int i = 0; i < SS; ++i) {
    float2 v = *(const float2*)(xs + i * LDX + tid * 2);
    sx += v.x; sy += v.y;
  }
  ((float2*)sums)[tid] = make_float2(sx, sy);
  const float mxs = sx * (1.0f / SS), mys = sy * (1.0f / SS);
  float m2 = mxs * mxs + mys * mys;
#pragma unroll
  for (int off = 32; off > 0; off >>= 1) m2 += __shfl_xor(m2, off, 64);
  if (lane == 0) red[wid] = m2;
  __syncthreads();
  if (tid == 0) snm = sqrtf(red[0] + red[1] + red[2] + red[3]);
  __syncthreads();
  const float inm = (1.0f / SS) / snm;
  {
    unsigned lo = f2bf(sx * inm), hi = f2bf(sy * inm);
    ((unsigned*)mrow)[tid] = lo | (hi << 16);   // bf16 mean row -> LDS
  }

  // per-row norms: one 16-lane group per row, all 16 rows parallel
  {
    const int g = tid >> 4, l16 = tid & 15;
    float nx2 = 0.f, dxs = 0.f, t2 = 0.f;
    const float2* xr2 = (const float2*)(xs + g * LDX);
    const float2* sm2 = (const float2*)sums;
#pragma unroll
    for (int t = 0; t < 16; ++t) {
      float2 xv = xr2[l16 + t * 16];
      float2 sc = sm2[l16 + t * 16];
      nx2 = fmaf(xv.x, xv.x, fmaf(xv.y, xv.y, nx2));
      dxs = fmaf(xv.x, sc.x, fmaf(xv.y, sc.y, dxs));
      float tx = sc.x - xv.x, ty = sc.y - xv.y;
      t2 = fmaf(tx, tx, fmaf(ty, ty, t2));
    }
#pragma unroll
    for (int off = 1; off < 16; off <<= 1) {
      nx2 += __shfl_xor(nx2, off, 64);
      dxs += __shfl_xor(dxs, off, 64);
      t2  += __shfl_xor(t2,  off, 64);
    }
    if (l16 == 0) {
      float nxv = sqrtf(nx2);
      float tn  = sqrtf(t2);
      float num = (dxs - nx2) * (1.0f / (SS - 1));
      float den = fmaxf(nxv * tn * (1.0f / (SS - 1)), EPSV);
      nx[j * SS + g] = nxv;
      rinv[g] = 1.0f / nxv;
      simpos[j * SS + g] = num / den;
    }
  }
  __syncthreads();   // mrow + rinv visible

  // scatter the mean row into B-fragment order (64 x 16B units)
  if (tid < 64) {
    const int kc = tid >> 2, quad = tid & 3;
    const uint4 u = *(const uint4*)&mrow[kc * 32 + quad * 8];
    ((uint4*)mnf)[(size_t)((j >> 4) * 16 + kc) * 64 + quad * 16 + (j & 15)] = u;
  }

  if (xn) {
    uint4* dst = (uint4*)xn + (size_t)j * 1024;  // 1024 16B units per class
#pragma unroll
    for (int t = 0; t < 4; ++t) {
      const int idxu = tid + t * 256;
      const int kc = idxu >> 6, quad = (idxu >> 4) & 3, cL = idxu & 15;
      const float* s = xs + cL * LDX + kc * 32 + quad * 8;
      const float4 a = *(const float4*)s;
      const float4 b2 = *(const float4*)(s + 4);
      const float ri = rinv[cL];
      uint4 o;
      o.x = (unsigned)f2bf(a.x * ri) | ((unsigned)f2bf(a.y * ri) << 16);
      o.y = (unsigned)f2bf(a.z * ri) | ((unsigned)f2bf(a.w * ri) << 16);
      o.z = (unsigned)f2bf(b2.x * ri) | ((unsigned)f2bf(b2.y * ri) << 16);
      o.w = (unsigned)f2bf(b2.z * ri) | ((unsigned)f2bf(b2.w * ri) << 16);
      dst[idxu] = o;
    }
  }
}

// ---------------- Kernel 2: MFMA GEMM + fused exp-sum, LDS-free ----------------
// 512 blocks x 128 thr (2 waves x 32 rows), 2 col-splits. NO __shared__,
// NO barriers: B-fragments load straight from fragment-ordered mnf
// (1KB coalesced wave-reads, L2/L1-resident). Occupancy ~8 waves/CU
// (VGPR-bound) hides the load latency that the old lockstep exposed.
template <bool USE_XN>
__global__ __launch_bounds__(128, 2) void k_gemm(
    const float* __restrict__ x, const ushort_t* __restrict__ xn,
    const ushort_t* __restrict__ mnf, const float* __restrict__ nx,
    const float* __restrict__ simpos, const float* __restrict__ wptr,
    const float* __restrict__ bptr, float* __restrict__ ps) {
  const int tid = threadIdx.x;
  const int wid = tid >> 6, lane = tid & 63;
  const int cL = lane & 15, quad = lane >> 4;
  const int bid = (int)blockIdx.x;
  const int rb = bid & 255, cb = bid >> 8;  // bid, bid+256 share XCD
  const int r0 = rb * 64, ft0 = cb * 32;
  const float wp = softplusf(wptr[0]), bv = bptr[0];
  const int row0w = r0 + wid * 32;

  short8 af[2][16];
  int jw[2];
  float sp[2][4], sacc[2][4];
#pragma unroll
  for (int rt = 0; rt < 2; ++rt) {
    jw[rt] = (row0w + rt * 16) >> 4;
    if (USE_XN) {
      const short8* xw = (const short8*)xn + (size_t)jw[rt] * 1024;
#pragma unroll
      for (int kc = 0; kc < 16; ++kc) af[rt][kc] = xw[kc * 64 + lane];
    } else {
      const int row = row0w + rt * 16 + cL;
      const float* xr = x + (size_t)row * DD;
      const float invn = 1.0f / nx[row];
#pragma unroll
      for (int kc = 0; kc < 16; ++kc) {
        const int k0 = kc * 32 + quad * 8;
        float4 p = *(const float4*)(xr + k0);
        float4 q = *(const float4*)(xr + k0 + 4);
        short8 v;
        v[0] = f2bf(p.x * invn); v[1] = f2bf(p.y * invn);
        v[2] = f2bf(p.z * invn); v[3] = f2bf(p.w * invn);
        v[4] = f2bf(q.x * invn); v[5] = f2bf(q.y * invn);
        v[6] = f2bf(q.z * invn); v[7] = f2bf(q.w * invn);
        af[rt][kc] = v;
      }
    }
#pragma unroll
    for (int r = 0; r < 4; ++r) {
      sp[rt][r] = simpos[row0w + rt * 16 + quad * 4 + r];
      sacc[rt][r] = 0.f;
    }
  }

  const short8* bbase = (const short8*)mnf + (size_t)ft0 * 1024 + lane;
  for (int f = 0; f < 32; ++f) {
    const short8* bp = bbase + (size_t)f * 1024;
    short8 bf[16];
#pragma unroll
    for (int kc = 0; kc < 16; ++kc) bf[kc] = bp[kc * 64];
    f32x4 acc[2];
#pragma unroll
    for (int rt = 0; rt < 2; ++rt) acc[rt] = (f32x4){0.f, 0.f, 0.f, 0.f};
#pragma unroll
    for (int kc = 0; kc < 16; ++kc) {
      acc[0] = __builtin_amdgcn_mfma_f32_16x16x32_bf16(af[0][kc], bf[kc],
                                                       acc[0], 0, 0, 0);
      acc[1] = __builtin_amdgcn_mfma_f32_16x16x32_bf16(af[1][kc], bf[kc],
                                                       acc[1], 0, 0, 0);
    }
    const int cg = (ft0 + f) * 16 + cL;
#pragma unroll
    for (int rt = 0; rt < 2; ++rt) {
      const bool diag = (cg == jw[rt]);
#pragma unroll
      for (int r = 0; r < 4; ++r) {
        const float sim = diag ? sp[rt][r] : acc[rt][r];
        sacc[rt][r] += __expf(fmaf(wp, sim, bv));
      }
    }
  }

#pragma unroll
  for (int rt = 0; rt < 2; ++rt)
#pragma unroll
    for (int r = 0; r < 4; ++r) {
      float v = sacc[rt][r];
#pragma unroll
      for (int off = 1; off < 16; off <<= 1) v += __shfl_xor(v, off, 64);
      if (cL == 0)
        ps[(size_t)(row0w + rt * 16 + quad * 4 + r) * 2 + cb] = v;
    }
}

// ---------------- tail: per-row loss + parallel reduce ----------------
__global__ __launch_bounds__(256) void k_combine(
    const float* __restrict__ ps, const float* __restrict__ simpos,
    const float* __restrict__ wptr, const float* __restrict__ bptr,
    float* __restrict__ p2) {
  __shared__ float red[4];
  const int tid = threadIdx.x;
  const int row = blockIdx.x * 256 + tid;
  const float wp = softplusf(wptr[0]), bv = bptr[0];
  const float2 v2 = ((const float2*)ps)[row];
  float v = logf(v2.x + v2.y) - fmaf(wp, simpos[row], bv);
#pragma unroll
  for (int off = 32; off > 0; off >>= 1) v += __shfl_xor(v, off, 64);
  if ((tid & 63) == 0) red[tid >> 6] = v;
  __syncthreads();
  if (tid == 0) p2[blockIdx.x] = red[0] + red[1] + red[2] + red[3];
}

__global__ __launch_bounds__(64) void k_fin(const float* __restrict__ p2,
                                            float* __restrict__ out) {
  const int tid = threadIdx.x;
  float v = p2[tid];
#pragma unroll
  for (int off = 32; off > 0; off >>= 1) v += __shfl_xor(v, off, 64);
  if (tid == 0) out[0] = v * (1.0f / RR);
}

extern "C" void kernel_launch(void* const* d_in, const int* in_sizes, int n_in,
                              void* d_out, int out_size, void* d_ws, size_t ws_size,
                              hipStream_t stream) {
  const float* x = (const float*)d_in[0];
  const float* w = (const float*)d_in[1];
  const float* b = (const float*)d_in[2];
  float* out = (float*)d_out;

  const size_t xn_bytes = (size_t)RR * DD * 2;  // 16 MB
  const size_t rest = (size_t)CC * DD * 2 + (size_t)RR * 4 * 2 +
                      (size_t)RR * 2 * 4 + 64 * 4;
  const bool use_xn = ws_size >= xn_bytes + rest + 256;

  char* base = (char*)d_ws;
  ushort_t* xn = use_xn ? (ushort_t*)base : nullptr;
  char* p = base + (use_xn ? xn_bytes : 0);
  ushort_t* mnf = (ushort_t*)p; p += (size_t)CC * DD * 2;   // 1 MB, frag-order
  float* nx     = (float*)p;    p += (size_t)RR * 4;
  float* simpos = (float*)p;    p += (size_t)RR * 4;
  float* ps     = (float*)p;    p += (size_t)RR * 2 * 4;
  float* p2     = (float*)p;

  k_pre<<<CC, 256, 0, stream>>>(x, mnf, nx, simpos, xn);
  if (use_xn)
    k_gemm<true><<<512, 128, 0, stream>>>(x, xn, mnf, nx, simpos, w, b, ps);
  else
    k_gemm<false><<<512, 128, 0, stream>>>(x, xn, mnf, nx, simpos, w, b, ps);
  k_combine<<<RR / 256, 256, 0, stream>>>(ps, simpos, w, b, p2);
  k_fin<<<1, 64, 0, stream>>>(p2, out);
}

// Round 10
// 109.877 us; speedup vs baseline: 1.4613x; 1.4613x over previous
//
#include <hip/hip_runtime.h>
#include <math.h>

#define CC 1024
#define SS 16
#define DD 512
#define RR (CC*SS)
#define EPSV 1e-8f
#define LDB 520    // B-tile row stride (shorts): bank-floor b128 reads
#define LDX 516    // k_pre LDS row stride (floats)
#define CHUNK 32   // cols per double-buffer half: 2*32*520*2 = 66.5 KB
#define NCHUNK 16  // 512 cols / 32

typedef __attribute__((ext_vector_type(8))) short short8;
typedef __attribute__((ext_vector_type(4))) float f32x4;
typedef unsigned short ushort_t;

__device__ __forceinline__ unsigned short f2bf(float f) {
  unsigned u = __float_as_uint(f);
  u += 0x7fffu + ((u >> 16) & 1u);  // RNE
  return (unsigned short)(u >> 16);
}

__device__ __forceinline__ void async16(void* l, const void* g) {
  __builtin_amdgcn_global_load_lds(
      (const __attribute__((address_space(1))) void*)g,
      (__attribute__((address_space(3))) void*)l, 16, 0, 0);
}

__device__ __forceinline__ float softplusf(float v) {
  return (v > 20.f) ? v : log1pf(expf(v));
}

#define SBAR()   __builtin_amdgcn_s_barrier()
#define SCHED0() __builtin_amdgcn_sched_barrier(0)

// ---------------- Kernel 1: per-class precompute (v2) ----------------
// Column sums fused into the load pass (register partials; pairwise
// combine) -- removes the separate 16x LDS-read pass. snm computed by
// all threads after one barrier. Norms pass float4. 3 barriers total.
// xn written in MFMA A-fragment order (16B units [class][kc][quad][cL]);
// mn row-major (k_gemm stages it via async16).
__global__ __launch_bounds__(256) void k_pre(
    const float* __restrict__ x, ushort_t* __restrict__ mn,
    float* __restrict__ nx, float* __restrict__ simpos,
    ushort_t* __restrict__ xn) {
  __shared__ float xs[SS * LDX];
  __shared__ float sums[DD];
  __shared__ float colpart[1024];
  __shared__ float red[4];
  __shared__ float rinv[SS];
  const int j = blockIdx.x, tid = threadIdx.x;
  const int wid = tid >> 6, lane = tid & 63;
  const float4* xj = (const float4*)(x + (size_t)j * SS * DD);

  // pass 1: load (8 coalesced float4 / thread: 8 rows x owned 4 cols)
  // + partial column sums in registers
  const int half = tid >> 7;      // 0: rows 0-7, 1: rows 8-15
  const int col4 = tid & 127;
  float4 cs = {0.f, 0.f, 0.f, 0.f};
#pragma unroll
  for (int i = 0; i < 8; ++i) {
    const int row = half * 8 + i;
    const float4 v = xj[row * 128 + col4];
    cs.x += v.x; cs.y += v.y; cs.z += v.z; cs.w += v.w;
    *(float4*)(xs + row * LDX + col4 * 4) = v;
  }
  ((float4*)colpart)[tid] = cs;
  __syncthreads();                      // barrier 1

  // pass 2: combine halves -> sums (LDS + regs), class-norm partial
  float4 s4 = {0.f, 0.f, 0.f, 0.f};
  float m2 = 0.f;
  if (tid < 128) {
    const float4 lo = ((const float4*)colpart)[tid];
    const float4 hi = ((const float4*)colpart)[tid + 128];
    s4.x = lo.x + hi.x; s4.y = lo.y + hi.y;
    s4.z = lo.z + hi.z; s4.w = lo.w + hi.w;
    ((float4*)sums)[tid] = s4;
    const float mx = s4.x * (1.f / SS), my = s4.y * (1.f / SS);
    const float mz = s4.z * (1.f / SS), mw = s4.w * (1.f / SS);
    m2 = mx * mx + my * my + mz * mz + mw * mw;
  }
#pragma unroll
  for (int off = 32; off > 0; off >>= 1) m2 += __shfl_xor(m2, off, 64);
  if (lane == 0) red[wid] = m2;         // waves 2,3 contribute 0
  __syncthreads();                      // barrier 2
  const float snm = sqrtf(red[0] + red[1] + red[2] + red[3]);
  const float inm = (1.0f / SS) / snm;
  if (tid < 128) {
    uint2 o;
    o.x = (unsigned)f2bf(s4.x * inm) | ((unsigned)f2bf(s4.y * inm) << 16);
    o.y = (unsigned)f2bf(s4.z * inm) | ((unsigned)f2bf(s4.w * inm) << 16);
    ((uint2*)(mn + (size_t)j * DD))[tid] = o;
  }

  // pass 3: per-row norms, one 16-lane group per row, float4 reads
  {
    const int g = tid >> 4, l16 = tid & 15;
    float nx2 = 0.f, dxs = 0.f, t2 = 0.f;
#pragma unroll
    for (int t = 0; t < 8; ++t) {
      const int c = l16 + t * 16;
      const float4 xv = *(const float4*)(xs + g * LDX + c * 4);
      const float4 sc = ((const float4*)sums)[c];
      nx2 = fmaf(xv.x, xv.x, fmaf(xv.y, xv.y,
            fmaf(xv.z, xv.z, fmaf(xv.w, xv.w, nx2))));
      dxs = fmaf(xv.x, sc.x, fmaf(xv.y, sc.y,
            fmaf(xv.z, sc.z, fmaf(xv.w, sc.w, dxs))));
      const float ax = sc.x - xv.x, ay = sc.y - xv.y;
      const float az = sc.z - xv.z, aw = sc.w - xv.w;
      t2 = fmaf(ax, ax, fmaf(ay, ay, fmaf(az, az, fmaf(aw, aw, t2))));
    }
#pragma unroll
    for (int off = 1; off < 16; off <<= 1) {
      nx2 += __shfl_xor(nx2, off, 64);
      dxs += __shfl_xor(dxs, off, 64);
      t2  += __shfl_xor(t2,  off, 64);
    }
    if (l16 == 0) {
      const float nxv = sqrtf(nx2);
      const float tn  = sqrtf(t2);
      const float num = (dxs - nx2) * (1.0f / (SS - 1));
      const float den = fmaxf(nxv * tn * (1.0f / (SS - 1)), EPSV);
      nx[j * SS + g] = nxv;
      rinv[g] = 1.0f / nxv;
      simpos[j * SS + g] = num / den;
    }
  }
  __syncthreads();                      // barrier 3 (rinv visible)

  // pass 4: xn in fragment order (reads xs, coalesced uint4 stores)
  if (xn) {
    uint4* dst = (uint4*)xn + (size_t)j * 1024;  // 1024 16B units per class
#pragma unroll
    for (int t = 0; t < 4; ++t) {
      const int idxu = tid + t * 256;
      const int kc = idxu >> 6, quad = (idxu >> 4) & 3, cL = idxu & 15;
      const float* s = xs + cL * LDX + kc * 32 + quad * 8;
      const float4 a = *(const float4*)s;
      const float4 b2 = *(const float4*)(s + 4);
      const float ri = rinv[cL];
      uint4 o;
      o.x = (unsigned)f2bf(a.x * ri) | ((unsigned)f2bf(a.y * ri) << 16);
      o.y = (unsigned)f2bf(a.z * ri) | ((unsigned)f2bf(a.w * ri) << 16);
      o.z = (unsigned)f2bf(b2.x * ri) | ((unsigned)f2bf(b2.y * ri) << 16);
      o.w = (unsigned)f2bf(b2.z * ri) | ((unsigned)f2bf(b2.w * ri) << 16);
      dst[idxu] = o;
    }
  }
}

// ---------------- Kernel 2: MFMA GEMM + fused exp-sum ----------------
// R7 structure (rt=2, 512 blocks x 128 thr, 2 col-splits, CHUNK=32
// counted-vmcnt double-buffer, fragment-ordered A loads) plus:
// (a) exp epilogue moved AFTER the release barrier -> runs in the shadow
//     of the next chunk's stage-issue + vmcnt wait;
// (b) s_setprio(1) around the ds_read+MFMA cluster (2 independent
//     blocks/CU provide the role diversity setprio arbitrates).
template <bool USE_XN>
__global__ __launch_bounds__(128, 2) void k_gemm(
    const float* __restrict__ x, const ushort_t* __restrict__ xn,
    const ushort_t* __restrict__ mn, const float* __restrict__ nx,
    const float* __restrict__ simpos, const float* __restrict__ wptr,
    const float* __restrict__ bptr, float* __restrict__ ps) {
  __shared__ ushort_t bs[2][CHUNK * LDB];  // 66.5 KB
  const int tid = threadIdx.x;
  const int wid = tid >> 6, lane = tid & 63;
  const int cL = lane & 15, quad = lane >> 4;
  const int bid = (int)blockIdx.x;
  const int rb = bid & 255, cb = bid >> 8;  // bid, bid+256 share XCD
  const int r0 = rb * 64, cbase = cb * 512;
  const float wp = softplusf(wptr[0]), bv = bptr[0];
  const int row0w = r0 + wid * 32;

  // stage chunk 0 first so its L2 latency overlaps the A-fragment loads
  {
    const ushort_t* gsrc = mn + (size_t)cbase * DD;
#pragma unroll
    for (int t = 0; t < 16; ++t) {
      const int rr = wid + t * 2;
      async16(&bs[0][rr * LDB + lane * 8], gsrc + (size_t)rr * DD + lane * 8);
    }
  }

  short8 af[2][16];
  int jw[2];
  float sp[2][4], sacc[2][4];
#pragma unroll
  for (int rt = 0; rt < 2; ++rt) {
    jw[rt] = (row0w + rt * 16) >> 4;
    if (USE_XN) {
      const short8* xw = (const short8*)xn + (size_t)jw[rt] * 1024;
#pragma unroll
      for (int kc = 0; kc < 16; ++kc) af[rt][kc] = xw[kc * 64 + lane];
    } else {
      const int row = row0w + rt * 16 + cL;
      const float* xr = x + (size_t)row * DD;
      const float invn = 1.0f / nx[row];
#pragma unroll
      for (int kc = 0; kc < 16; ++kc) {
        const int k0 = kc * 32 + quad * 8;
        float4 p = *(const float4*)(xr + k0);
        float4 q = *(const float4*)(xr + k0 + 4);
        short8 v;
        v[0] = f2bf(p.x * invn); v[1] = f2bf(p.y * invn);
        v[2] = f2bf(p.z * invn); v[3] = f2bf(p.w * invn);
        v[4] = f2bf(q.x * invn); v[5] = f2bf(q.y * invn);
        v[6] = f2bf(q.z * invn); v[7] = f2bf(q.w * invn);
        af[rt][kc] = v;
      }
    }
#pragma unroll
    for (int r = 0; r < 4; ++r) {
      sp[rt][r] = simpos[row0w + rt * 16 + quad * 4 + r];
      sacc[rt][r] = 0.f;
    }
  }

#pragma unroll
  for (int cc = 0; cc < NCHUNK; ++cc) {
    if (cc < NCHUNK - 1) {
      const ushort_t* gsrc = mn + (size_t)(cbase + (cc + 1) * CHUNK) * DD;
      ushort_t* dst = bs[(cc + 1) & 1];
#pragma unroll
      for (int t = 0; t < 16; ++t) {
        const int rr = wid + t * 2;
        async16(&dst[rr * LDB + lane * 8], gsrc + (size_t)rr * DD + lane * 8);
      }
      SCHED0();
      asm volatile("s_waitcnt vmcnt(16)" ::: "memory");
    } else {
      asm volatile("s_waitcnt vmcnt(0)" ::: "memory");
    }
    SCHED0();
    SBAR();   // all waves' chunk-cc loads landed
    SCHED0();

    const ushort_t* B = bs[cc & 1];
    f32x4 acc[2][2];
#pragma unroll
    for (int rt = 0; rt < 2; ++rt)
#pragma unroll
      for (int f = 0; f < 2; ++f) acc[rt][f] = (f32x4){0.f, 0.f, 0.f, 0.f};
    __builtin_amdgcn_s_setprio(1);
#pragma unroll
    for (int kc = 0; kc < 16; ++kc) {
      short8 bfr[2];
#pragma unroll
      for (int f = 0; f < 2; ++f)
        bfr[f] = *(const short8*)&B[(f * 16 + cL) * LDB + kc * 32 + quad * 8];
#pragma unroll
      for (int rt = 0; rt < 2; ++rt)
#pragma unroll
        for (int f = 0; f < 2; ++f)
          acc[rt][f] = __builtin_amdgcn_mfma_f32_16x16x32_bf16(
              af[rt][kc], bfr[f], acc[rt][f], 0, 0, 0);
    }
    __builtin_amdgcn_s_setprio(0);
    // release the buffer BEFORE the exp epilogue: the epilogue (register
    // -only) then runs in the shadow of the next iteration's stage+wait.
    if (cc < NCHUNK - 1) {
      SCHED0();
      SBAR();
      SCHED0();
    }
    const int c0 = cbase + cc * CHUNK;
#pragma unroll
    for (int rt = 0; rt < 2; ++rt)
#pragma unroll
      for (int f = 0; f < 2; ++f) {
        const int cg = c0 + f * 16 + cL;
        const bool diag = (cg == jw[rt]);
#pragma unroll
        for (int r = 0; r < 4; ++r) {
          const float sim = diag ? sp[rt][r] : acc[rt][f][r];
          sacc[rt][r] += __expf(fmaf(wp, sim, bv));
        }
      }
  }

#pragma unroll
  for (int rt = 0; rt < 2; ++rt)
#pragma unroll
    for (int r = 0; r < 4; ++r) {
      float v = sacc[rt][r];
#pragma unroll
      for (int off = 1; off < 16; off <<= 1) v += __shfl_xor(v, off, 64);
      if (cL == 0)
        ps[(size_t)(row0w + rt * 16 + quad * 4 + r) * 2 + cb] = v;
    }
}

// ---------------- tail: per-row loss + parallel reduce ----------------
__global__ __launch_bounds__(256) void k_combine(
    const float* __restrict__ ps, const float* __restrict__ simpos,
    const float* __restrict__ wptr, const float* __restrict__ bptr,
    float* __restrict__ p2) {
  __shared__ float red[4];
  const int tid = threadIdx.x;
  const int row = blockIdx.x * 256 + tid;
  const float wp = softplusf(wptr[0]), bv = bptr[0];
  const float2 v2 = ((const float2*)ps)[row];
  float v = logf(v2.x + v2.y) - fmaf(wp, simpos[row], bv);
#pragma unroll
  for (int off = 32; off > 0; off >>= 1) v += __shfl_xor(v, off, 64);
  if ((tid & 63) == 0) red[tid >> 6] = v;
  __syncthreads();
  if (tid == 0) p2[blockIdx.x] = red[0] + red[1] + red[2] + red[3];
}

__global__ __launch_bounds__(64) void k_fin(const float* __restrict__ p2,
                                            float* __restrict__ out) {
  const int tid = threadIdx.x;
  float v = p2[tid];
#pragma unroll
  for (int off = 32; off > 0; off >>= 1) v += __shfl_xor(v, off, 64);
  if (tid == 0) out[0] = v * (1.0f / RR);
}

extern "C" void kernel_launch(void* const* d_in, const int* in_sizes, int n_in,
                              void* d_out, int out_size, void* d_ws, size_t ws_size,
                              hipStream_t stream) {
  const float* x = (const float*)d_in[0];
  const float* w = (const float*)d_in[1];
  const float* b = (const float*)d_in[2];
  float* out = (float*)d_out;

  const size_t xn_bytes = (size_t)RR * DD * 2;  // 16 MB
  const size_t rest = (size_t)CC * DD * 2 + (size_t)RR * 4 * 2 +
                      (size_t)RR * 2 * 4 + 64 * 4;
  const bool use_xn = ws_size >= xn_bytes + rest + 256;

  char* base = (char*)d_ws;
  ushort_t* xn = use_xn ? (ushort_t*)base : nullptr;
  char* p = base + (use_xn ? xn_bytes : 0);
  ushort_t* mn = (ushort_t*)p;  p += (size_t)CC * DD * 2;
  float* nx     = (float*)p;    p += (size_t)RR * 4;
  float* simpos = (float*)p;    p += (size_t)RR * 4;
  float* ps     = (float*)p;    p += (size_t)RR * 2 * 4;
  float* p2     = (float*)p;

  k_pre<<<CC, 256, 0, stream>>>(x, mn, nx, simpos, xn);
  if (use_xn)
    k_gemm<true><<<512, 128, 0, stream>>>(x, xn, mn, nx, simpos, w, b, ps);
  else
    k_gemm<false><<<512, 128, 0, stream>>>(x, xn, mn, nx, simpos, w, b, ps);
  k_combine<<<RR / 256, 256, 0, stream>>>(ps, simpos, w, b, p2);
  k_fin<<<1, 64, 0, stream>>>(p2, out);
}

// Round 11
// 108.668 us; speedup vs baseline: 1.4776x; 1.0111x over previous
//
#include <hip/hip_runtime.h>
#include <math.h>

#define CC 1024
#define SS 16
#define DD 512
#define RR (CC*SS)
#define EPSV 1e-8f
#define LDB 520    // B-tile row stride (shorts): bank-floor b128 reads
#define LDX 516    // k_pre LDS row stride (floats)
#define CHUNK 16   // cols per double-buffer half: 2*16*520*2 = 33.3 KB -> 4 blk/CU
#define NCHUNK 16  // 256 cols per split / 16

typedef __attribute__((ext_vector_type(8))) short short8;
typedef __attribute__((ext_vector_type(4))) float f32x4;
typedef unsigned short ushort_t;

__device__ __forceinline__ unsigned short f2bf(float f) {
  unsigned u = __float_as_uint(f);
  u += 0x7fffu + ((u >> 16) & 1u);  // RNE
  return (unsigned short)(u >> 16);
}

__device__ __forceinline__ void async16(void* l, const void* g) {
  __builtin_amdgcn_global_load_lds(
      (const __attribute__((address_space(1))) void*)g,
      (__attribute__((address_space(3))) void*)l, 16, 0, 0);
}

__device__ __forceinline__ float softplusf(float v) {
  return (v > 20.f) ? v : log1pf(expf(v));
}

#define SBAR()   __builtin_amdgcn_s_barrier()
#define SCHED0() __builtin_amdgcn_sched_barrier(0)

// ---------------- Kernel 1: per-class precompute (v2, unchanged) ----------------
__global__ __launch_bounds__(256) void k_pre(
    const float* __restrict__ x, ushort_t* __restrict__ mn,
    float* __restrict__ nx, float* __restrict__ simpos,
    ushort_t* __restrict__ xn) {
  __shared__ float xs[SS * LDX];
  __shared__ float sums[DD];
  __shared__ float colpart[1024];
  __shared__ float red[4];
  __shared__ float rinv[SS];
  const int j = blockIdx.x, tid = threadIdx.x;
  const int wid = tid >> 6, lane = tid & 63;
  const float4* xj = (const float4*)(x + (size_t)j * SS * DD);

  // pass 1: load (8 coalesced float4 / thread) + column partials in regs
  const int half = tid >> 7;
  const int col4 = tid & 127;
  float4 cs = {0.f, 0.f, 0.f, 0.f};
#pragma unroll
  for (int i = 0; i < 8; ++i) {
    const int row = half * 8 + i;
    const float4 v = xj[row * 128 + col4];
    cs.x += v.x; cs.y += v.y; cs.z += v.z; cs.w += v.w;
    *(float4*)(xs + row * LDX + col4 * 4) = v;
  }
  ((float4*)colpart)[tid] = cs;
  __syncthreads();

  // pass 2: combine halves -> sums, class-norm partial, mn write
  float4 s4 = {0.f, 0.f, 0.f, 0.f};
  float m2 = 0.f;
  if (tid < 128) {
    const float4 lo = ((const float4*)colpart)[tid];
    const float4 hi = ((const float4*)colpart)[tid + 128];
    s4.x = lo.x + hi.x; s4.y = lo.y + hi.y;
    s4.z = lo.z + hi.z; s4.w = lo.w + hi.w;
    ((float4*)sums)[tid] = s4;
    const float mx = s4.x * (1.f / SS), my = s4.y * (1.f / SS);
    const float mz = s4.z * (1.f / SS), mw = s4.w * (1.f / SS);
    m2 = mx * mx + my * my + mz * mz + mw * mw;
  }
#pragma unroll
  for (int off = 32; off > 0; off >>= 1) m2 += __shfl_xor(m2, off, 64);
  if (lane == 0) red[wid] = m2;
  __syncthreads();
  const float snm = sqrtf(red[0] + red[1] + red[2] + red[3]);
  const float inm = (1.0f / SS) / snm;
  if (tid < 128) {
    uint2 o;
    o.x = (unsigned)f2bf(s4.x * inm) | ((unsigned)f2bf(s4.y * inm) << 16);
    o.y = (unsigned)f2bf(s4.z * inm) | ((unsigned)f2bf(s4.w * inm) << 16);
    ((uint2*)(mn + (size_t)j * DD))[tid] = o;
  }

  // pass 3: per-row norms, one 16-lane group per row
  {
    const int g = tid >> 4, l16 = tid & 15;
    float nx2 = 0.f, dxs = 0.f, t2 = 0.f;
#pragma unroll
    for (int t = 0; t < 8; ++t) {
      const int c = l16 + t * 16;
      const float4 xv = *(const float4*)(xs + g * LDX + c * 4);
      const float4 sc = ((const float4*)sums)[c];
      nx2 = fmaf(xv.x, xv.x, fmaf(xv.y, xv.y,
            fmaf(xv.z, xv.z, fmaf(xv.w, xv.w, nx2))));
      dxs = fmaf(xv.x, sc.x, fmaf(xv.y, sc.y,
            fmaf(xv.z, sc.z, fmaf(xv.w, sc.w, dxs))));
      const float ax = sc.x - xv.x, ay = sc.y - xv.y;
      const float az = sc.z - xv.z, aw = sc.w - xv.w;
      t2 = fmaf(ax, ax, fmaf(ay, ay, fmaf(az, az, fmaf(aw, aw, t2))));
    }
#pragma unroll
    for (int off = 1; off < 16; off <<= 1) {
      nx2 += __shfl_xor(nx2, off, 64);
      dxs += __shfl_xor(dxs, off, 64);
      t2  += __shfl_xor(t2,  off, 64);
    }
    if (l16 == 0) {
      const float nxv = sqrtf(nx2);
      const float tn  = sqrtf(t2);
      const float num = (dxs - nx2) * (1.0f / (SS - 1));
      const float den = fmaxf(nxv * tn * (1.0f / (SS - 1)), EPSV);
      nx[j * SS + g] = nxv;
      rinv[g] = 1.0f / nxv;
      simpos[j * SS + g] = num / den;
    }
  }
  __syncthreads();

  // pass 4: xn in MFMA A-fragment order
  if (xn) {
    uint4* dst = (uint4*)xn + (size_t)j * 1024;
#pragma unroll
    for (int t = 0; t < 4; ++t) {
      const int idxu = tid + t * 256;
      const int kc = idxu >> 6, quad = (idxu >> 4) & 3, cL = idxu & 15;
      const float* s = xs + cL * LDX + kc * 32 + quad * 8;
      const float4 a = *(const float4*)s;
      const float4 b2 = *(const float4*)(s + 4);
      const float ri = rinv[cL];
      uint4 o;
      o.x = (unsigned)f2bf(a.x * ri) | ((unsigned)f2bf(a.y * ri) << 16);
      o.y = (unsigned)f2bf(a.z * ri) | ((unsigned)f2bf(a.w * ri) << 16);
      o.z = (unsigned)f2bf(b2.x * ri) | ((unsigned)f2bf(b2.y * ri) << 16);
      o.w = (unsigned)f2bf(b2.z * ri) | ((unsigned)f2bf(b2.w * ri) << 16);
      dst[idxu] = o;
    }
  }
}

// ---------------- Kernel 2: MFMA GEMM + fused exp-sum ----------------
// NEW GEOMETRY: 1024 blocks x 128 thr (2 waves x 32 rows), 4 col-splits
// of 256 cols, CHUNK=16 double-buffer (33.3 KB) -> 4 blocks/CU -> 8
// waves/CU -> 2 waves/SIMD. Combines counted-vmcnt (R4) with real TLP
// (R1) for the first time: a wave stalled on vmcnt/ds_read latency now
// has a SIMD-mate to run through the stall. Epilogue before release
// barrier (R7 ordering), no setprio.
template <bool USE_XN>
__global__ __launch_bounds__(128, 2) void k_gemm(
    const float* __restrict__ x, const ushort_t* __restrict__ xn,
    const ushort_t* __restrict__ mn, const float* __restrict__ nx,
    const float* __restrict__ simpos, const float* __restrict__ wptr,
    const float* __restrict__ bptr, float* __restrict__ ps) {
  __shared__ ushort_t bs[2][CHUNK * LDB];  // 33.3 KB
  const int tid = threadIdx.x;
  const int wid = tid >> 6, lane = tid & 63;
  const int cL = lane & 15, quad = lane >> 4;
  const int bid = (int)blockIdx.x;
  const int rb = bid & 255, cb = bid >> 8;  // sharers bid+256k: same XCD
  const int r0 = rb * 64, cbase = cb * 256;
  const float wp = softplusf(wptr[0]), bv = bptr[0];
  const int row0w = r0 + wid * 32;

  // stage chunk 0 first so its latency overlaps the A-fragment loads
  {
    const ushort_t* gsrc = mn + (size_t)cbase * DD;
#pragma unroll
    for (int t = 0; t < 8; ++t) {
      const int rr = wid + t * 2;
      async16(&bs[0][rr * LDB + lane * 8], gsrc + (size_t)rr * DD + lane * 8);
    }
  }

  short8 af[2][16];
  int jw[2];
  float sp[2][4], sacc[2][4];
#pragma unroll
  for (int rt = 0; rt < 2; ++rt) {
    jw[rt] = (row0w + rt * 16) >> 4;
    if (USE_XN) {
      const short8* xw = (const short8*)xn + (size_t)jw[rt] * 1024;
#pragma unroll
      for (int kc = 0; kc < 16; ++kc) af[rt][kc] = xw[kc * 64 + lane];
    } else {
      const int row = row0w + rt * 16 + cL;
      const float* xr = x + (size_t)row * DD;
      const float invn = 1.0f / nx[row];
#pragma unroll
      for (int kc = 0; kc < 16; ++kc) {
        const int k0 = kc * 32 + quad * 8;
        float4 p = *(const float4*)(xr + k0);
        float4 q = *(const float4*)(xr + k0 + 4);
        short8 v;
        v[0] = f2bf(p.x * invn); v[1] = f2bf(p.y * invn);
        v[2] = f2bf(p.z * invn); v[3] = f2bf(p.w * invn);
        v[4] = f2bf(q.x * invn); v[5] = f2bf(q.y * invn);
        v[6] = f2bf(q.z * invn); v[7] = f2bf(q.w * invn);
        af[rt][kc] = v;
      }
    }
#pragma unroll
    for (int r = 0; r < 4; ++r) {
      sp[rt][r] = simpos[row0w + rt * 16 + quad * 4 + r];
      sacc[rt][r] = 0.f;
    }
  }

#pragma unroll
  for (int cc = 0; cc < NCHUNK; ++cc) {
    if (cc < NCHUNK - 1) {
      const ushort_t* gsrc = mn + (size_t)(cbase + (cc + 1) * CHUNK) * DD;
      ushort_t* dst = bs[(cc + 1) & 1];
#pragma unroll
      for (int t = 0; t < 8; ++t) {
        const int rr = wid + t * 2;
        async16(&dst[rr * LDB + lane * 8], gsrc + (size_t)rr * DD + lane * 8);
      }
      SCHED0();
      asm volatile("s_waitcnt vmcnt(8)" ::: "memory");  // chunk-cc's 8 landed
    } else {
      asm volatile("s_waitcnt vmcnt(0)" ::: "memory");
    }
    SCHED0();
    SBAR();
    SCHED0();

    const ushort_t* B = bs[cc & 1];
    f32x4 acc[2];
    acc[0] = (f32x4){0.f, 0.f, 0.f, 0.f};
    acc[1] = (f32x4){0.f, 0.f, 0.f, 0.f};
#pragma unroll
    for (int kc = 0; kc < 16; ++kc) {
      const short8 bfr =
          *(const short8*)&B[cL * LDB + kc * 32 + quad * 8];
      acc[0] = __builtin_amdgcn_mfma_f32_16x16x32_bf16(af[0][kc], bfr,
                                                       acc[0], 0, 0, 0);
      acc[1] = __builtin_amdgcn_mfma_f32_16x16x32_bf16(af[1][kc], bfr,
                                                       acc[1], 0, 0, 0);
    }
    const int c0 = cbase + cc * CHUNK;
#pragma unroll
    for (int rt = 0; rt < 2; ++rt) {
      const int cg = c0 + cL;
      const bool diag = (cg == jw[rt]);
#pragma unroll
      for (int r = 0; r < 4; ++r) {
        const float sim = diag ? sp[rt][r] : acc[rt][r];
        sacc[rt][r] += __expf(fmaf(wp, sim, bv));
      }
    }
    if (cc < NCHUNK - 1) {
      SCHED0();
      SBAR();   // all waves done reading bs[cc&1]
      SCHED0();
    }
  }

#pragma unroll
  for (int rt = 0; rt < 2; ++rt)
#pragma unroll
    for (int r = 0; r < 4; ++r) {
      float v = sacc[rt][r];
#pragma unroll
      for (int off = 1; off < 16; off <<= 1) v += __shfl_xor(v, off, 64);
      if (cL == 0)
        ps[(size_t)(row0w + rt * 16 + quad * 4 + r) * 4 + cb] = v;
    }
}

// ---------------- tail: per-row loss + parallel reduce ----------------
__global__ __launch_bounds__(256) void k_combine(
    const float* __restrict__ ps, const float* __restrict__ simpos,
    const float* __restrict__ wptr, const float* __restrict__ bptr,
    float* __restrict__ p2) {
  __shared__ float red[4];
  const int tid = threadIdx.x;
  const int row = blockIdx.x * 256 + tid;
  const float wp = softplusf(wptr[0]), bv = bptr[0];
  const f32x4 v4 = ((const f32x4*)ps)[row];
  const float s = (v4[0] + v4[1]) + (v4[2] + v4[3]);
  float v = logf(s) - fmaf(wp, simpos[row], bv);
#pragma unroll
  for (int off = 32; off > 0; off >>= 1) v += __shfl_xor(v, off, 64);
  if ((tid & 63) == 0) red[tid >> 6] = v;
  __syncthreads();
  if (tid == 0) p2[blockIdx.x] = red[0] + red[1] + red[2] + red[3];
}

__global__ __launch_bounds__(64) void k_fin(const float* __restrict__ p2,
                                            float* __restrict__ out) {
  const int tid = threadIdx.x;
  float v = p2[tid];
#pragma unroll
  for (int off = 32; off > 0; off >>= 1) v += __shfl_xor(v, off, 64);
  if (tid == 0) out[0] = v * (1.0f / RR);
}

extern "C" void kernel_launch(void* const* d_in, const int* in_sizes, int n_in,
                              void* d_out, int out_size, void* d_ws, size_t ws_size,
                              hipStream_t stream) {
  const float* x = (const float*)d_in[0];
  const float* w = (const float*)d_in[1];
  const float* b = (const float*)d_in[2];
  float* out = (float*)d_out;

  const size_t xn_bytes = (size_t)RR * DD * 2;  // 16 MB
  const size_t rest = (size_t)CC * DD * 2 + (size_t)RR * 4 * 2 +
                      (size_t)RR * 4 * 4 + 64 * 4;
  const bool use_xn = ws_size >= xn_bytes + rest + 256;

  char* base = (char*)d_ws;
  ushort_t* xn = use_xn ? (ushort_t*)base : nullptr;
  char* p = base + (use_xn ? xn_bytes : 0);
  ushort_t* mn = (ushort_t*)p;  p += (size_t)CC * DD * 2;
  float* nx     = (float*)p;    p += (size_t)RR * 4;
  float* simpos = (float*)p;    p += (size_t)RR * 4;
  float* ps     = (float*)p;    p += (size_t)RR * 4 * 4;
  float* p2     = (float*)p;

  k_pre<<<CC, 256, 0, stream>>>(x, mn, nx, simpos, xn);
  if (use_xn)
    k_gemm<true><<<1024, 128, 0, stream>>>(x, xn, mn, nx, simpos, w, b, ps);
  else
    k_gemm<false><<<1024, 128, 0, stream>>>(x, xn, mn, nx, simpos, w, b, ps);
  k_combine<<<RR / 256, 256, 0, stream>>>(ps, simpos, w, b, p2);
  k_fin<<<1, 64, 0, stream>>>(p2, out);
}